// Round 9
// baseline (199.065 us; speedup 1.0000x reference)
//
#include <hip/hip_runtime.h>
#include <hip/hip_bf16.h>

#define N_USERS   100000
#define EMBED_DIM 128
#define N_EDGES   640000
#define ZERO_ROW  N_USERS          // embb row of zeros (pad target)
#define SLOTS     32               // fixed perm capacity per node (max deg << 32)

typedef __bf16 bf16x8 __attribute__((ext_vector_type(8)));
typedef float  f32x4  __attribute__((ext_vector_type(4)));

// ---- workspace layout (bytes) ----
// [0,          25,600,256)  embb   bf16 [100001][128] (row 100000 = zeros)
// [25,600,256, 26,000,256)  cursor int  [100000]  (scatter cursor == degree)
// [26,000,384, 38,800,384)  perm   int  [100000][32] fixed slots (tails padded
//                                                     x4 with ZERO_ROW by the
//                                                     owning k_fused block)
// [38,800,384, 38,833,152)  wlsw   bf16 [16384]  Wl in MFMA-fragment order
// [38,833,152, 38,865,920)  wrsw   bf16 [16384]  Wr in MFMA-fragment order
#define OFF_CURSOR 25600256
#define OFF_PERM   26000384
#define OFF_WLSW   38800384
#define OFF_WRSW   38833152

__device__ __forceinline__ unsigned short f2bf_rne(float f) {
    union { float f; unsigned u; } c; c.f = f;
    unsigned u = c.u + 0x7fffu + ((c.u >> 16) & 1u);
    return (unsigned short)(u >> 16);
}
__device__ __forceinline__ float bf2f_lo(unsigned u) {
    union { float f; unsigned u; } c; c.u = u << 16;
    return c.f;
}
__device__ __forceinline__ float bf2f_hi(unsigned u) {
    union { float f; unsigned u; } c; c.u = u & 0xffff0000u;
    return c.f;
}

// Merged prep (R6-proven): emb -> embb (bf16), zero-row, W_l/W_r MFMA-fragment
// swizzle, AND the edge scatter into fixed per-node slots
// (pos = atomicAdd(cursor[dst])).  cursor pre-zeroed by hipMemsetAsync.
// wsw[((jt*4+kt)*64 + lane)*8 + j] = W[jt*16+(lane&15)][kt*32+(lane>>4)*8+j]
// grid: 6250 x 256
__global__ __launch_bounds__(256) void k_init(const float* __restrict__ emb,
                                              const float* __restrict__ Wl,
                                              const float* __restrict__ Wr,
                                              const int* __restrict__ src,
                                              const int* __restrict__ dst,
                                              unsigned short* __restrict__ embb,
                                              int* __restrict__ cursor,
                                              int* __restrict__ perm,
                                              unsigned short* __restrict__ wlsw,
                                              unsigned short* __restrict__ wrsw) {
    int i = blockIdx.x * 256 + threadIdx.x;
    if (i < 2048) {    // 2048 threads x 8 elems = 16384 = one W table
        int li = i & 63;            // lane
        int kt = (i >> 6) & 3;
        int jt = i >> 8;            // 0..7
        int row  = jt * 16 + (li & 15);
        int colb = kt * 32 + ((li >> 4) << 3);
        const float4* pl = (const float4*)(Wl + row * 128 + colb);
        const float4* pr = (const float4*)(Wr + row * 128 + colb);
        float4 l0 = pl[0], l1 = pl[1];
        float4 r0 = pr[0], r1 = pr[1];
        int o = i * 8;
        wlsw[o+0] = f2bf_rne(l0.x); wlsw[o+1] = f2bf_rne(l0.y);
        wlsw[o+2] = f2bf_rne(l0.z); wlsw[o+3] = f2bf_rne(l0.w);
        wlsw[o+4] = f2bf_rne(l1.x); wlsw[o+5] = f2bf_rne(l1.y);
        wlsw[o+6] = f2bf_rne(l1.z); wlsw[o+7] = f2bf_rne(l1.w);
        wrsw[o+0] = f2bf_rne(r0.x); wrsw[o+1] = f2bf_rne(r0.y);
        wrsw[o+2] = f2bf_rne(r0.z); wrsw[o+3] = f2bf_rne(r0.w);
        wrsw[o+4] = f2bf_rne(r1.x); wrsw[o+5] = f2bf_rne(r1.y);
        wrsw[o+6] = f2bf_rne(r1.z); wrsw[o+7] = f2bf_rne(r1.w);
    }
    // zero row at index N_USERS: 128 bf16 = 256 B = exactly 16 int4.
    if (i < 16) {
        int4 z = {0, 0, 0, 0};
        ((int4*)(embb + (size_t)ZERO_ROW * EMBED_DIM))[i] = z;
    }
    // emb -> embb, 8 floats per thread
    float4 a = ((const float4*)emb)[i * 2 + 0];
    float4 b = ((const float4*)emb)[i * 2 + 1];
    int4 p;
    p.x = (int)f2bf_rne(a.x) | ((int)f2bf_rne(a.y) << 16);
    p.y = (int)f2bf_rne(a.z) | ((int)f2bf_rne(a.w) << 16);
    p.z = (int)f2bf_rne(b.x) | ((int)f2bf_rne(b.y) << 16);
    p.w = (int)f2bf_rne(b.z) | ((int)f2bf_rne(b.w) << 16);
    ((int4*)embb)[i] = p;
    // edge scatter into fixed slots (pos guard is paranoia; max deg << 32)
    if (i < N_EDGES) {
        int d = dst[i];
        int pos = atomicAdd(&cursor[d], 1);
        if (pos < SLOTS) perm[d * SLOTS + pos] = src[i];
    }
}

// FUSED aggregate + matmul: block = 32 nodes x 128 cols, 4 waves.
// Top: block pads ITS OWN 32 perm rows' slot tails to x4 with ZERO_ROW.
// Phase 1 (gather): R1's branch-free pair-interleave (4B/lane, 8 row-requests
//   in flight, x2 unroll; pads contribute 0.0). No atomics, no half-wave,
//   no cooperative launch (R2/R4/R5/R7 lessons).
// Phase 2 (MFMA): af from sa; ef DIRECTLY from embb (L3-resident); W from
//   pre-swizzled tables.
// Epilogue (NEW, R8 lesson): the old 4B/lane stores wrote 64B segments into
//   128B lines -> read-allocate fetched the ENTIRE 50MB output back from HBM
//   (FETCH_SIZE 89.4MB vs ~39MB of legitimate reads). Now each rt's acc tile
//   is staged in so[16][132] fp32 LDS (2-way bank alias, free), then copied
//   out as float4/lane -- 1KB contiguous per wave instruction, full lines,
//   no read-allocate. LDS total 17.2KB (sa 8.7 + so 8.4) -> still 8+ blocks/CU.
// grid: 3125 x 256
#define LDS_S 136
#define SO_S  132
__global__ __launch_bounds__(256) void k_fused(const unsigned short* __restrict__ embb,
                                               const int* __restrict__ cursor,
                                               int* __restrict__ perm,
                                               const unsigned short* __restrict__ wlsw,
                                               const unsigned short* __restrict__ wrsw,
                                               const float* __restrict__ bl,
                                               float* __restrict__ out) {
    __shared__ unsigned short sa[32 * LDS_S];   // 8,704 B bf16 neighbor means
    __shared__ float          so[16 * SO_S];    // 8,448 B fp32 epilogue tile
    int tid  = threadIdx.x;
    int wave = tid >> 6;
    int lane = tid & 63;
    int quad = lane >> 4;      // 0..3
    int m    = lane & 15;
    int node0 = blockIdx.x * 32;
    int off   = lane * 2;      // 4 B (2 shorts) per lane; 64 lanes = 256 B row

    // ---- pad OWN nodes' slot tails to x4 with ZERO_ROW (exclusive rows) ----
    if (tid < 32) {
        int n = node0 + tid;
        int c = cursor[n]; c = c < SLOTS ? c : SLOTS;
        int ce = (c + 3) & ~3;
        for (int k = c; k < ce; k++) perm[n * SLOTS + k] = ZERO_ROW;
    }
    __syncthreads();   // pads visible to this block's loads

    // ---- all 8 node degrees up front (L2-hot, independent loads) ----
    int nb = node0 + wave * 8;
    int cN[8];
#pragma unroll
    for (int r = 0; r < 8; r++) {
        int c = cursor[nb + r];
        cN[r] = c < SLOTS ? c : SLOTS;
    }

    const unsigned short* ep = embb;

    // ---- phase 1: R1's branch-free pair-interleaved gather ----
#pragma unroll
    for (int p = 0; p < 4; p++) {
        int nA = p * 2, nB = nA + 1;
        const int4* gA = (const int4*)(perm + (nb + nA) * SLOTS);
        const int4* gB = (const int4*)(perm + (nb + nB) * SLOTS);
        int ga = (cN[nA] + 3) >> 2;
        int gb = (cN[nB] + 3) >> 2;
        int gmin = ga < gb ? ga : gb;
        float2 accA = {0.f, 0.f}, accB = {0.f, 0.f};
        int t = 0;
#pragma unroll 2
        for (; t < gmin; t++) {                // 8 row-requests in flight
            int4 ia = gA[t];                   // wave-uniform broadcast
            int4 ib = gB[t];
            unsigned a0 = *(const unsigned*)(ep + (size_t)ia.x * EMBED_DIM + off);
            unsigned a1 = *(const unsigned*)(ep + (size_t)ia.y * EMBED_DIM + off);
            unsigned a2 = *(const unsigned*)(ep + (size_t)ia.z * EMBED_DIM + off);
            unsigned a3 = *(const unsigned*)(ep + (size_t)ia.w * EMBED_DIM + off);
            unsigned b0 = *(const unsigned*)(ep + (size_t)ib.x * EMBED_DIM + off);
            unsigned b1 = *(const unsigned*)(ep + (size_t)ib.y * EMBED_DIM + off);
            unsigned b2 = *(const unsigned*)(ep + (size_t)ib.z * EMBED_DIM + off);
            unsigned b3 = *(const unsigned*)(ep + (size_t)ib.w * EMBED_DIM + off);
            accA.x += (bf2f_lo(a0) + bf2f_lo(a1)) + (bf2f_lo(a2) + bf2f_lo(a3));
            accA.y += (bf2f_hi(a0) + bf2f_hi(a1)) + (bf2f_hi(a2) + bf2f_hi(a3));
            accB.x += (bf2f_lo(b0) + bf2f_lo(b1)) + (bf2f_lo(b2) + bf2f_lo(b3));
            accB.y += (bf2f_hi(b0) + bf2f_hi(b1)) + (bf2f_hi(b2) + bf2f_hi(b3));
        }
        for (int ta = t; ta < ga; ta++) {
            int4 ia = gA[ta];
            unsigned a0 = *(const unsigned*)(ep + (size_t)ia.x * EMBED_DIM + off);
            unsigned a1 = *(const unsigned*)(ep + (size_t)ia.y * EMBED_DIM + off);
            unsigned a2 = *(const unsigned*)(ep + (size_t)ia.z * EMBED_DIM + off);
            unsigned a3 = *(const unsigned*)(ep + (size_t)ia.w * EMBED_DIM + off);
            accA.x += (bf2f_lo(a0) + bf2f_lo(a1)) + (bf2f_lo(a2) + bf2f_lo(a3));
            accA.y += (bf2f_hi(a0) + bf2f_hi(a1)) + (bf2f_hi(a2) + bf2f_hi(a3));
        }
        for (int tb = t; tb < gb; tb++) {
            int4 ib = gB[tb];
            unsigned b0 = *(const unsigned*)(ep + (size_t)ib.x * EMBED_DIM + off);
            unsigned b1 = *(const unsigned*)(ep + (size_t)ib.y * EMBED_DIM + off);
            unsigned b2 = *(const unsigned*)(ep + (size_t)ib.z * EMBED_DIM + off);
            unsigned b3 = *(const unsigned*)(ep + (size_t)ib.w * EMBED_DIM + off);
            accB.x += (bf2f_lo(b0) + bf2f_lo(b1)) + (bf2f_lo(b2) + bf2f_lo(b3));
            accB.y += (bf2f_hi(b0) + bf2f_hi(b1)) + (bf2f_hi(b2) + bf2f_hi(b3));
        }
        float invA = (cN[nA] > 0) ? 1.0f / (float)cN[nA] : 0.0f;
        float invB = (cN[nB] > 0) ? 1.0f / (float)cN[nB] : 0.0f;
        unsigned oA = (unsigned)f2bf_rne(accA.x * invA) | ((unsigned)f2bf_rne(accA.y * invA) << 16);
        unsigned oB = (unsigned)f2bf_rne(accB.x * invB) | ((unsigned)f2bf_rne(accB.y * invB) << 16);
        *(unsigned*)(sa + (wave * 8 + nA) * LDS_S + off) = oA;
        *(unsigned*)(sa + (wave * 8 + nB) * LDS_S + off) = oB;
    }

    // ---- W fragments + bias (latency hides under the barrier wait) ----
    int jt0 = wave * 2;
    bf16x8 wl[2][4], wr[2][4];
#pragma unroll
    for (int jj = 0; jj < 2; jj++) {
#pragma unroll
        for (int kt = 0; kt < 4; kt++) {
            size_t o = (size_t)((((jt0 + jj) * 4 + kt) * 64 + lane)) * 8;
            wl[jj][kt] = *(const bf16x8*)((const __bf16*)wlsw + o);
            wr[jj][kt] = *(const bf16x8*)((const __bf16*)wrsw + o);
        }
    }
    float bias[2];
    bias[0] = bl[(jt0 + 0) * 16 + m];
    bias[1] = bl[(jt0 + 1) * 16 + m];

    __syncthreads();   // all waves' flushes visible

    // ---- phase 2: af from sa; ef straight from embb; MFMA; staged store ----
#pragma unroll
    for (int rt = 0; rt < 2; rt++) {
        bf16x8 af[4], ef[4];
#pragma unroll
        for (int kt = 0; kt < 4; kt++) {
            int o = (rt * 16 + m) * LDS_S + kt * 32 + quad * 8;
            af[kt] = *(const bf16x8*)(sa + o);
            ef[kt] = *(const bf16x8*)(embb + (size_t)(node0 + rt * 16 + m) * EMBED_DIM
                                      + kt * 32 + quad * 8);
        }
        f32x4 acc[2] = {{0.f,0.f,0.f,0.f}, {0.f,0.f,0.f,0.f}};
#pragma unroll
        for (int kt = 0; kt < 4; kt++) {
#pragma unroll
            for (int jj = 0; jj < 2; jj++) {
                acc[jj] = __builtin_amdgcn_mfma_f32_16x16x32_bf16(af[kt], wl[jj][kt], acc[jj], 0, 0, 0);
                acc[jj] = __builtin_amdgcn_mfma_f32_16x16x32_bf16(ef[kt], wr[jj][kt], acc[jj], 0, 0, 0);
            }
        }
        // C/D layout: col = lane&15, row = quad*4 + reg.
        // Stage the 16x128 fp32 tile in LDS, then store full-line float4s.
#pragma unroll
        for (int jj = 0; jj < 2; jj++) {
#pragma unroll
            for (int r = 0; r < 4; r++) {
                so[(quad * 4 + r) * SO_S + (jt0 + jj) * 16 + m] = acc[jj][r] + bias[jj];
            }
        }
        __syncthreads();   // tile complete
#pragma unroll
        for (int pp = 0; pp < 2; pp++) {
            int g   = pp * 256 + tid;          // 512 float4 chunks = 8 KB
            int row = g >> 5;                  // 0..15
            int c   = g & 31;                  // float4 index within row
            float4 v = *(const float4*)(so + row * SO_S + c * 4);
            *(float4*)(out + (size_t)(node0 + rt * 16 + row) * EMBED_DIM + c * 4) = v;
        }
        if (rt == 0) __syncthreads();          // protect so before rt=1 writes
    }
}

extern "C" void kernel_launch(void* const* d_in, const int* in_sizes, int n_in,
                              void* d_out, int out_size, void* d_ws, size_t ws_size,
                              hipStream_t stream) {
    const float* emb = (const float*)d_in[0];
    const float* Wl  = (const float*)d_in[1];
    const float* bl  = (const float*)d_in[2];
    const float* Wr  = (const float*)d_in[3];
    const int*   src = (const int*)d_in[4];
    const int*   dst = (const int*)d_in[5];
    float* out = (float*)d_out;

    char* ws = (char*)d_ws;
    unsigned short* embb   = (unsigned short*)ws;
    int*            cursor = (int*)(ws + OFF_CURSOR);
    int*            perm   = (int*)(ws + OFF_PERM);
    unsigned short* wlsw   = (unsigned short*)(ws + OFF_WLSW);
    unsigned short* wrsw   = (unsigned short*)(ws + OFF_WRSW);

    // zero scatter cursors (graph-capturable memset node)
    hipMemsetAsync(ws + OFF_CURSOR, 0, 400000, stream);

    k_init<<<6250, 256, 0, stream>>>(emb, Wl, Wr, src, dst, embb, cursor, perm, wlsw, wrsw);
    k_fused<<<3125, 256, 0, stream>>>(embb, cursor, perm, wlsw, wrsw, bl, out);
}

// Round 10
// 184.120 us; speedup vs baseline: 1.0812x; 1.0812x over previous
//
#include <hip/hip_runtime.h>
#include <hip/hip_bf16.h>

#define N_USERS   100000
#define EMBED_DIM 128
#define N_EDGES   640000
#define ZERO_ROW  N_USERS          // embb row of zeros (pad target)
#define SLOTS     32               // fixed perm capacity per node (max deg << 32)

typedef __bf16 bf16x8 __attribute__((ext_vector_type(8)));
typedef float  f32x4  __attribute__((ext_vector_type(4)));

// ---- workspace layout (bytes) ----
// [0,          25,600,256)  embb   bf16 [100001][128] (row 100000 = zeros)
// [25,600,256, 26,000,256)  cursor int  [100000]  (scatter cursor == degree)
// [26,000,384, 38,800,384)  perm   int  [100000][32] fixed slots (tails padded
//                                                     x4 with ZERO_ROW by the
//                                                     owning k_fused block)
// [38,800,384, 38,833,152)  wlsw   bf16 [16384]  Wl in MFMA-fragment order
// [38,833,152, 38,865,920)  wrsw   bf16 [16384]  Wr in MFMA-fragment order
#define OFF_CURSOR 25600256
#define OFF_PERM   26000384
#define OFF_WLSW   38800384
#define OFF_WRSW   38833152

__device__ __forceinline__ unsigned short f2bf_rne(float f) {
    union { float f; unsigned u; } c; c.f = f;
    unsigned u = c.u + 0x7fffu + ((c.u >> 16) & 1u);
    return (unsigned short)(u >> 16);
}
__device__ __forceinline__ float bf2f_lo(unsigned u) {
    union { float f; unsigned u; } c; c.u = u << 16;
    return c.f;
}
__device__ __forceinline__ float bf2f_hi(unsigned u) {
    union { float f; unsigned u; } c; c.u = u & 0xffff0000u;
    return c.f;
}

// Merged prep (R6-proven): emb -> embb (bf16), zero-row, W_l/W_r MFMA-fragment
// swizzle, AND the edge scatter into fixed per-node slots
// (pos = atomicAdd(cursor[dst])).  cursor pre-zeroed by hipMemsetAsync.
// wsw[((jt*4+kt)*64 + lane)*8 + j] = W[jt*16+(lane&15)][kt*32+(lane>>4)*8+j]
// grid: 6250 x 256
__global__ __launch_bounds__(256) void k_init(const float* __restrict__ emb,
                                              const float* __restrict__ Wl,
                                              const float* __restrict__ Wr,
                                              const int* __restrict__ src,
                                              const int* __restrict__ dst,
                                              unsigned short* __restrict__ embb,
                                              int* __restrict__ cursor,
                                              int* __restrict__ perm,
                                              unsigned short* __restrict__ wlsw,
                                              unsigned short* __restrict__ wrsw) {
    int i = blockIdx.x * 256 + threadIdx.x;
    if (i < 2048) {    // 2048 threads x 8 elems = 16384 = one W table
        int li = i & 63;            // lane
        int kt = (i >> 6) & 3;
        int jt = i >> 8;            // 0..7
        int row  = jt * 16 + (li & 15);
        int colb = kt * 32 + ((li >> 4) << 3);
        const float4* pl = (const float4*)(Wl + row * 128 + colb);
        const float4* pr = (const float4*)(Wr + row * 128 + colb);
        float4 l0 = pl[0], l1 = pl[1];
        float4 r0 = pr[0], r1 = pr[1];
        int o = i * 8;
        wlsw[o+0] = f2bf_rne(l0.x); wlsw[o+1] = f2bf_rne(l0.y);
        wlsw[o+2] = f2bf_rne(l0.z); wlsw[o+3] = f2bf_rne(l0.w);
        wlsw[o+4] = f2bf_rne(l1.x); wlsw[o+5] = f2bf_rne(l1.y);
        wlsw[o+6] = f2bf_rne(l1.z); wlsw[o+7] = f2bf_rne(l1.w);
        wrsw[o+0] = f2bf_rne(r0.x); wrsw[o+1] = f2bf_rne(r0.y);
        wrsw[o+2] = f2bf_rne(r0.z); wrsw[o+3] = f2bf_rne(r0.w);
        wrsw[o+4] = f2bf_rne(r1.x); wrsw[o+5] = f2bf_rne(r1.y);
        wrsw[o+6] = f2bf_rne(r1.z); wrsw[o+7] = f2bf_rne(r1.w);
    }
    // zero row at index N_USERS: 128 bf16 = 256 B = exactly 16 int4.
    if (i < 16) {
        int4 z = {0, 0, 0, 0};
        ((int4*)(embb + (size_t)ZERO_ROW * EMBED_DIM))[i] = z;
    }
    // emb -> embb, 8 floats per thread
    float4 a = ((const float4*)emb)[i * 2 + 0];
    float4 b = ((const float4*)emb)[i * 2 + 1];
    int4 p;
    p.x = (int)f2bf_rne(a.x) | ((int)f2bf_rne(a.y) << 16);
    p.y = (int)f2bf_rne(a.z) | ((int)f2bf_rne(a.w) << 16);
    p.z = (int)f2bf_rne(b.x) | ((int)f2bf_rne(b.y) << 16);
    p.w = (int)f2bf_rne(b.z) | ((int)f2bf_rne(b.w) << 16);
    ((int4*)embb)[i] = p;
    // edge scatter into fixed slots (pos guard is paranoia; max deg << 32)
    if (i < N_EDGES) {
        int d = dst[i];
        int pos = atomicAdd(&cursor[d], 1);
        if (pos < SLOTS) perm[d * SLOTS + pos] = src[i];
    }
}

// FUSED aggregate + matmul: block = 32 nodes x 128 cols, 4 waves.
// Top: issue the two 8KB self-slab loads (ve0/ve1) FIRST -- their latency
//   hides under the pad stores + barrier + gather (R1's proven pattern,
//   dropped in R6-R9; restoring it is this round's single change). Then the
//   block pads ITS OWN 32 perm rows' slot tails to x4 with ZERO_ROW.
// Phase 1 (gather): R1's branch-free pair-interleave (4B/lane, 8 row-requests
//   in flight, x2 unroll; pads contribute 0.0). No atomics, no half-wave,
//   no cooperative launch (R2/R4/R5/R7 lessons).
// Phase 2 (MFMA): af from sa; ef from the se LDS slab (NOT direct-embb --
//   R6-R9's 32 scattered 16B ef loads sat exposed between barrier and MFMA;
//   R1's slab+LDS form measured ~10us faster). W from pre-swizzled tables.
//   Direct 4B out stores (R8/R9 proved LDS-staged epilogue neutral).
// LDS: sa 8.7KB + se 8.7KB = 17.4KB -> 8 blocks/CU by wave slots.
// grid: 3125 x 256
#define LDS_S 136
__global__ __launch_bounds__(256) void k_fused(const unsigned short* __restrict__ embb,
                                               const int* __restrict__ cursor,
                                               int* __restrict__ perm,
                                               const unsigned short* __restrict__ wlsw,
                                               const unsigned short* __restrict__ wrsw,
                                               const float* __restrict__ bl,
                                               float* __restrict__ out) {
    __shared__ unsigned short sa[32 * LDS_S];   // 8,704 B bf16 neighbor means
    __shared__ unsigned short se[32 * LDS_S];   // 8,704 B bf16 self rows
    int tid  = threadIdx.x;
    int wave = tid >> 6;
    int lane = tid & 63;
    int quad = lane >> 4;      // 0..3
    int m    = lane & 15;
    int node0 = blockIdx.x * 32;
    int off   = lane * 2;      // 4 B (2 shorts) per lane; 64 lanes = 256 B row

    // ---- issue self-slab loads FIRST: 2 x 8 KB contiguous, hidden under
    //      pad+barrier+gather ----
    const int4* eslab = (const int4*)(embb + (size_t)node0 * EMBED_DIM);
    int4 ve0 = eslab[tid];
    int4 ve1 = eslab[256 + tid];

    // ---- pad OWN nodes' slot tails to x4 with ZERO_ROW (exclusive rows) ----
    if (tid < 32) {
        int n = node0 + tid;
        int c = cursor[n]; c = c < SLOTS ? c : SLOTS;
        int ce = (c + 3) & ~3;
        for (int k = c; k < ce; k++) perm[n * SLOTS + k] = ZERO_ROW;
    }
    __syncthreads();   // pads visible to this block's loads

    // ---- all 8 node degrees up front (L2-hot, independent loads) ----
    int nb = node0 + wave * 8;
    int cN[8];
#pragma unroll
    for (int r = 0; r < 8; r++) {
        int c = cursor[nb + r];
        cN[r] = c < SLOTS ? c : SLOTS;
    }

    const unsigned short* ep = embb;

    // ---- phase 1: R1's branch-free pair-interleaved gather ----
#pragma unroll
    for (int p = 0; p < 4; p++) {
        int nA = p * 2, nB = nA + 1;
        const int4* gA = (const int4*)(perm + (nb + nA) * SLOTS);
        const int4* gB = (const int4*)(perm + (nb + nB) * SLOTS);
        int ga = (cN[nA] + 3) >> 2;
        int gb = (cN[nB] + 3) >> 2;
        int gmin = ga < gb ? ga : gb;
        float2 accA = {0.f, 0.f}, accB = {0.f, 0.f};
        int t = 0;
#pragma unroll 2
        for (; t < gmin; t++) {                // 8 row-requests in flight
            int4 ia = gA[t];                   // wave-uniform broadcast
            int4 ib = gB[t];
            unsigned a0 = *(const unsigned*)(ep + (size_t)ia.x * EMBED_DIM + off);
            unsigned a1 = *(const unsigned*)(ep + (size_t)ia.y * EMBED_DIM + off);
            unsigned a2 = *(const unsigned*)(ep + (size_t)ia.z * EMBED_DIM + off);
            unsigned a3 = *(const unsigned*)(ep + (size_t)ia.w * EMBED_DIM + off);
            unsigned b0 = *(const unsigned*)(ep + (size_t)ib.x * EMBED_DIM + off);
            unsigned b1 = *(const unsigned*)(ep + (size_t)ib.y * EMBED_DIM + off);
            unsigned b2 = *(const unsigned*)(ep + (size_t)ib.z * EMBED_DIM + off);
            unsigned b3 = *(const unsigned*)(ep + (size_t)ib.w * EMBED_DIM + off);
            accA.x += (bf2f_lo(a0) + bf2f_lo(a1)) + (bf2f_lo(a2) + bf2f_lo(a3));
            accA.y += (bf2f_hi(a0) + bf2f_hi(a1)) + (bf2f_hi(a2) + bf2f_hi(a3));
            accB.x += (bf2f_lo(b0) + bf2f_lo(b1)) + (bf2f_lo(b2) + bf2f_lo(b3));
            accB.y += (bf2f_hi(b0) + bf2f_hi(b1)) + (bf2f_hi(b2) + bf2f_hi(b3));
        }
        for (int ta = t; ta < ga; ta++) {
            int4 ia = gA[ta];
            unsigned a0 = *(const unsigned*)(ep + (size_t)ia.x * EMBED_DIM + off);
            unsigned a1 = *(const unsigned*)(ep + (size_t)ia.y * EMBED_DIM + off);
            unsigned a2 = *(const unsigned*)(ep + (size_t)ia.z * EMBED_DIM + off);
            unsigned a3 = *(const unsigned*)(ep + (size_t)ia.w * EMBED_DIM + off);
            accA.x += (bf2f_lo(a0) + bf2f_lo(a1)) + (bf2f_lo(a2) + bf2f_lo(a3));
            accA.y += (bf2f_hi(a0) + bf2f_hi(a1)) + (bf2f_hi(a2) + bf2f_hi(a3));
        }
        for (int tb = t; tb < gb; tb++) {
            int4 ib = gB[tb];
            unsigned b0 = *(const unsigned*)(ep + (size_t)ib.x * EMBED_DIM + off);
            unsigned b1 = *(const unsigned*)(ep + (size_t)ib.y * EMBED_DIM + off);
            unsigned b2 = *(const unsigned*)(ep + (size_t)ib.z * EMBED_DIM + off);
            unsigned b3 = *(const unsigned*)(ep + (size_t)ib.w * EMBED_DIM + off);
            accB.x += (bf2f_lo(b0) + bf2f_lo(b1)) + (bf2f_lo(b2) + bf2f_lo(b3));
            accB.y += (bf2f_hi(b0) + bf2f_hi(b1)) + (bf2f_hi(b2) + bf2f_hi(b3));
        }
        float invA = (cN[nA] > 0) ? 1.0f / (float)cN[nA] : 0.0f;
        float invB = (cN[nB] > 0) ? 1.0f / (float)cN[nB] : 0.0f;
        unsigned oA = (unsigned)f2bf_rne(accA.x * invA) | ((unsigned)f2bf_rne(accA.y * invA) << 16);
        unsigned oB = (unsigned)f2bf_rne(accB.x * invB) | ((unsigned)f2bf_rne(accB.y * invB) << 16);
        *(unsigned*)(sa + (wave * 8 + nA) * LDS_S + off) = oA;
        *(unsigned*)(sa + (wave * 8 + nB) * LDS_S + off) = oB;
    }

    // ---- write self slab to LDS (loads issued at kernel top) ----
    {
        int g = tid, row = g >> 4, c = g & 15;
        *(int4*)(se + row * LDS_S + c * 8) = ve0;
        g = 256 + tid; row = g >> 4; c = g & 15;
        *(int4*)(se + row * LDS_S + c * 8) = ve1;
    }

    // ---- W fragments + bias (latency hides under the barrier wait) ----
    int jt0 = wave * 2;
    bf16x8 wl[2][4], wr[2][4];
#pragma unroll
    for (int jj = 0; jj < 2; jj++) {
#pragma unroll
        for (int kt = 0; kt < 4; kt++) {
            size_t o = (size_t)((((jt0 + jj) * 4 + kt) * 64 + lane)) * 8;
            wl[jj][kt] = *(const bf16x8*)((const __bf16*)wlsw + o);
            wr[jj][kt] = *(const bf16x8*)((const __bf16*)wrsw + o);
        }
    }
    float bias[2];
    bias[0] = bl[(jt0 + 0) * 16 + m];
    bias[1] = bl[(jt0 + 1) * 16 + m];

    __syncthreads();   // all waves' sa flushes + se writes visible

    // ---- phase 2: af from sa; ef from se; MFMA; direct store ----
#pragma unroll
    for (int rt = 0; rt < 2; rt++) {
        bf16x8 af[4], ef[4];
#pragma unroll
        for (int kt = 0; kt < 4; kt++) {
            int o = (rt * 16 + m) * LDS_S + kt * 32 + quad * 8;
            af[kt] = *(const bf16x8*)(sa + o);
            ef[kt] = *(const bf16x8*)(se + o);
        }
        f32x4 acc[2] = {{0.f,0.f,0.f,0.f}, {0.f,0.f,0.f,0.f}};
#pragma unroll
        for (int kt = 0; kt < 4; kt++) {
#pragma unroll
            for (int jj = 0; jj < 2; jj++) {
                acc[jj] = __builtin_amdgcn_mfma_f32_16x16x32_bf16(af[kt], wl[jj][kt], acc[jj], 0, 0, 0);
                acc[jj] = __builtin_amdgcn_mfma_f32_16x16x32_bf16(ef[kt], wr[jj][kt], acc[jj], 0, 0, 0);
            }
        }
        // C/D layout: col = lane&15, row = quad*4 + reg
#pragma unroll
        for (int jj = 0; jj < 2; jj++) {
#pragma unroll
            for (int r = 0; r < 4; r++) {
                int orow = node0 + rt * 16 + quad * 4 + r;
                out[(size_t)orow * EMBED_DIM + (jt0 + jj) * 16 + m] = acc[jj][r] + bias[jj];
            }
        }
    }
}

extern "C" void kernel_launch(void* const* d_in, const int* in_sizes, int n_in,
                              void* d_out, int out_size, void* d_ws, size_t ws_size,
                              hipStream_t stream) {
    const float* emb = (const float*)d_in[0];
    const float* Wl  = (const float*)d_in[1];
    const float* bl  = (const float*)d_in[2];
    const float* Wr  = (const float*)d_in[3];
    const int*   src = (const int*)d_in[4];
    const int*   dst = (const int*)d_in[5];
    float* out = (float*)d_out;

    char* ws = (char*)d_ws;
    unsigned short* embb   = (unsigned short*)ws;
    int*            cursor = (int*)(ws + OFF_CURSOR);
    int*            perm   = (int*)(ws + OFF_PERM);
    unsigned short* wlsw   = (unsigned short*)(ws + OFF_WLSW);
    unsigned short* wrsw   = (unsigned short*)(ws + OFF_WRSW);

    // zero scatter cursors (graph-capturable memset node)
    hipMemsetAsync(ws + OFF_CURSOR, 0, 400000, stream);

    k_init<<<6250, 256, 0, stream>>>(emb, Wl, Wr, src, dst, embb, cursor, perm, wlsw, wrsw);
    k_fused<<<3125, 256, 0, stream>>>(embb, cursor, perm, wlsw, wrsw, bl, out);
}

// Round 11
// 181.841 us; speedup vs baseline: 1.0947x; 1.0125x over previous
//
#include <hip/hip_runtime.h>
#include <hip/hip_bf16.h>

#define N_USERS   100000
#define EMBED_DIM 128
#define N_EDGES   640000
#define ZERO_ROW  N_USERS          // embb row of zeros (pad target)
#define SLOTS     32               // fixed perm capacity per node (max deg << 32)
#define NWIN      2500             // 256-edge windows
#define GRID_INIT 20000            // 8 class-blocks per window

typedef __bf16 bf16x8 __attribute__((ext_vector_type(8)));
typedef float  f32x4  __attribute__((ext_vector_type(4)));

// ---- workspace layout (bytes) ----
// [0,          25,600,256)  embb   bf16 [100001][128] (row 100000 = zeros)
// [25,600,256, 26,000,256)  cursor int  [100000]  (scatter cursor == degree)
// [26,000,384, 38,800,384)  perm   int  [100000][32] fixed slots (tails padded
//                                                     x4 with ZERO_ROW by the
//                                                     owning k_fused block)
// [38,800,384, 38,833,152)  wlsw   bf16 [16384]  Wl in MFMA-fragment order
// [38,833,152, 38,865,920)  wrsw   bf16 [16384]  Wr in MFMA-fragment order
#define OFF_CURSOR 25600256
#define OFF_PERM   26000384
#define OFF_WLSW   38800384
#define OFF_WRSW   38833152

__device__ __forceinline__ unsigned short f2bf_rne(float f) {
    union { float f; unsigned u; } c; c.f = f;
    unsigned u = c.u + 0x7fffu + ((c.u >> 16) & 1u);
    return (unsigned short)(u >> 16);
}
__device__ __forceinline__ float bf2f_lo(unsigned u) {
    union { float f; unsigned u; } c; c.u = u << 16;
    return c.f;
}
__device__ __forceinline__ float bf2f_hi(unsigned u) {
    union { float f; unsigned u; } c; c.u = u & 0xffff0000u;
    return c.f;
}

// Prep with XCD-PARTITIONED scatter (R10 lesson: k_init was 62us vs 14.5us
// traffic floor -- cross-XCD bouncing of cursor lines (~102 atomics/64B line
// from 8 XCDs) and perm lines (WRITE_SIZE 63MB = ~3x eviction/line)).
// Edge phase: window w = b>>3 (256 edges), class c = b&7. The 8 blocks
// sharing a window land on 8 different XCDs (blockIdx%8 round-robin -- speed
// heuristic only, correctness-independent); block keeps edges with
// ((dst>>4)&7)==c, so each cursor line (16 nodes) and its 16 perm rows are
// written from exactly ONE XCD class. Window reads are 8x-amplified but
// edge data is L3-resident (~5MB).
// Conversion phase (blocks < 6250): emb -> embb bf16, zero-row, W_l/W_r
// MFMA-fragment swizzle -- unchanged, rides along.
// cursor pre-zeroed by hipMemsetAsync.  grid: 20000 x 256
__global__ __launch_bounds__(256) void k_init(const float* __restrict__ emb,
                                              const float* __restrict__ Wl,
                                              const float* __restrict__ Wr,
                                              const int* __restrict__ src,
                                              const int* __restrict__ dst,
                                              unsigned short* __restrict__ embb,
                                              int* __restrict__ cursor,
                                              int* __restrict__ perm,
                                              unsigned short* __restrict__ wlsw,
                                              unsigned short* __restrict__ wrsw) {
    int b   = blockIdx.x;
    int tid = threadIdx.x;

    // ---- edge scatter, XCD-class-filtered ----
    {
        int w = b >> 3;            // window 0..2499
        int cls = b & 7;           // XCD class
        int e = w * 256 + tid;     // covers 0..639,999 exactly
        int d = dst[e];
        if (((d >> 4) & 7) == cls) {
            int pos = atomicAdd(&cursor[d], 1);
            if (pos < SLOTS) perm[d * SLOTS + pos] = src[e];
        }
    }

    // ---- conversion + W swizzle (blocks < 6250 only) ----
    if (b < 6250) {
        int i = b * 256 + tid;
        if (i < 2048) {    // 2048 threads x 8 elems = 16384 = one W table
            int li = i & 63;            // lane
            int kt = (i >> 6) & 3;
            int jt = i >> 8;            // 0..7
            int row  = jt * 16 + (li & 15);
            int colb = kt * 32 + ((li >> 4) << 3);
            const float4* pl = (const float4*)(Wl + row * 128 + colb);
            const float4* pr = (const float4*)(Wr + row * 128 + colb);
            float4 l0 = pl[0], l1 = pl[1];
            float4 r0 = pr[0], r1 = pr[1];
            int o = i * 8;
            wlsw[o+0] = f2bf_rne(l0.x); wlsw[o+1] = f2bf_rne(l0.y);
            wlsw[o+2] = f2bf_rne(l0.z); wlsw[o+3] = f2bf_rne(l0.w);
            wlsw[o+4] = f2bf_rne(l1.x); wlsw[o+5] = f2bf_rne(l1.y);
            wlsw[o+6] = f2bf_rne(l1.z); wlsw[o+7] = f2bf_rne(l1.w);
            wrsw[o+0] = f2bf_rne(r0.x); wrsw[o+1] = f2bf_rne(r0.y);
            wrsw[o+2] = f2bf_rne(r0.z); wrsw[o+3] = f2bf_rne(r0.w);
            wrsw[o+4] = f2bf_rne(r1.x); wrsw[o+5] = f2bf_rne(r1.y);
            wrsw[o+6] = f2bf_rne(r1.z); wrsw[o+7] = f2bf_rne(r1.w);
        }
        // zero row at index N_USERS: 128 bf16 = 256 B = exactly 16 int4.
        if (i < 16) {
            int4 z = {0, 0, 0, 0};
            ((int4*)(embb + (size_t)ZERO_ROW * EMBED_DIM))[i] = z;
        }
        // emb -> embb, 8 floats per thread
        float4 a = ((const float4*)emb)[i * 2 + 0];
        float4 bb = ((const float4*)emb)[i * 2 + 1];
        int4 p;
        p.x = (int)f2bf_rne(a.x)  | ((int)f2bf_rne(a.y)  << 16);
        p.y = (int)f2bf_rne(a.z)  | ((int)f2bf_rne(a.w)  << 16);
        p.z = (int)f2bf_rne(bb.x) | ((int)f2bf_rne(bb.y) << 16);
        p.w = (int)f2bf_rne(bb.z) | ((int)f2bf_rne(bb.w) << 16);
        ((int4*)embb)[i] = p;
    }
}

// FUSED aggregate + matmul: block = 32 nodes x 128 cols, 4 waves.
// (R10's proven structure, unchanged: 54.5us measured.)
// Top: issue the two 8KB self-slab loads (ve0/ve1) FIRST (latency hides under
//   pad stores + barrier + gather); block pads ITS OWN 32 perm rows to x4.
// Phase 1: R1's branch-free pair-interleave gather (4B/lane, 8 row-requests
//   in flight, x2 unroll; pads contribute 0.0). No atomics, no half-wave,
//   no cooperative launch (R2/R4/R5/R7 lessons).
// Phase 2: af from sa; ef from se LDS slab (R10: direct-embb ef cost ~8us);
//   W from pre-swizzled tables; direct 4B out stores (R9: staged epilogue
//   neutral -- the 89MB FETCH is gather L2 misses, not write-allocate).
// LDS: sa 8.7KB + se 8.7KB = 17.4KB.
// grid: 3125 x 256
#define LDS_S 136
__global__ __launch_bounds__(256) void k_fused(const unsigned short* __restrict__ embb,
                                               const int* __restrict__ cursor,
                                               int* __restrict__ perm,
                                               const unsigned short* __restrict__ wlsw,
                                               const unsigned short* __restrict__ wrsw,
                                               const float* __restrict__ bl,
                                               float* __restrict__ out) {
    __shared__ unsigned short sa[32 * LDS_S];   // 8,704 B bf16 neighbor means
    __shared__ unsigned short se[32 * LDS_S];   // 8,704 B bf16 self rows
    int tid  = threadIdx.x;
    int wave = tid >> 6;
    int lane = tid & 63;
    int quad = lane >> 4;      // 0..3
    int m    = lane & 15;
    int node0 = blockIdx.x * 32;
    int off   = lane * 2;      // 4 B (2 shorts) per lane; 64 lanes = 256 B row

    // ---- issue self-slab loads FIRST: 2 x 8 KB contiguous ----
    const int4* eslab = (const int4*)(embb + (size_t)node0 * EMBED_DIM);
    int4 ve0 = eslab[tid];
    int4 ve1 = eslab[256 + tid];

    // ---- pad OWN nodes' slot tails to x4 with ZERO_ROW (exclusive rows) ----
    if (tid < 32) {
        int n = node0 + tid;
        int c = cursor[n]; c = c < SLOTS ? c : SLOTS;
        int ce = (c + 3) & ~3;
        for (int k = c; k < ce; k++) perm[n * SLOTS + k] = ZERO_ROW;
    }
    __syncthreads();   // pads visible to this block's loads

    // ---- all 8 node degrees up front (L2-hot, independent loads) ----
    int nb = node0 + wave * 8;
    int cN[8];
#pragma unroll
    for (int r = 0; r < 8; r++) {
        int c = cursor[nb + r];
        cN[r] = c < SLOTS ? c : SLOTS;
    }

    const unsigned short* ep = embb;

    // ---- phase 1: R1's branch-free pair-interleaved gather ----
#pragma unroll
    for (int p = 0; p < 4; p++) {
        int nA = p * 2, nB = nA + 1;
        const int4* gA = (const int4*)(perm + (nb + nA) * SLOTS);
        const int4* gB = (const int4*)(perm + (nb + nB) * SLOTS);
        int ga = (cN[nA] + 3) >> 2;
        int gb = (cN[nB] + 3) >> 2;
        int gmin = ga < gb ? ga : gb;
        float2 accA = {0.f, 0.f}, accB = {0.f, 0.f};
        int t = 0;
#pragma unroll 2
        for (; t < gmin; t++) {                // 8 row-requests in flight
            int4 ia = gA[t];                   // wave-uniform broadcast
            int4 ib = gB[t];
            unsigned a0 = *(const unsigned*)(ep + (size_t)ia.x * EMBED_DIM + off);
            unsigned a1 = *(const unsigned*)(ep + (size_t)ia.y * EMBED_DIM + off);
            unsigned a2 = *(const unsigned*)(ep + (size_t)ia.z * EMBED_DIM + off);
            unsigned a3 = *(const unsigned*)(ep + (size_t)ia.w * EMBED_DIM + off);
            unsigned b0 = *(const unsigned*)(ep + (size_t)ib.x * EMBED_DIM + off);
            unsigned b1 = *(const unsigned*)(ep + (size_t)ib.y * EMBED_DIM + off);
            unsigned b2 = *(const unsigned*)(ep + (size_t)ib.z * EMBED_DIM + off);
            unsigned b3 = *(const unsigned*)(ep + (size_t)ib.w * EMBED_DIM + off);
            accA.x += (bf2f_lo(a0) + bf2f_lo(a1)) + (bf2f_lo(a2) + bf2f_lo(a3));
            accA.y += (bf2f_hi(a0) + bf2f_hi(a1)) + (bf2f_hi(a2) + bf2f_hi(a3));
            accB.x += (bf2f_lo(b0) + bf2f_lo(b1)) + (bf2f_lo(b2) + bf2f_lo(b3));
            accB.y += (bf2f_hi(b0) + bf2f_hi(b1)) + (bf2f_hi(b2) + bf2f_hi(b3));
        }
        for (int ta = t; ta < ga; ta++) {
            int4 ia = gA[ta];
            unsigned a0 = *(const unsigned*)(ep + (size_t)ia.x * EMBED_DIM + off);
            unsigned a1 = *(const unsigned*)(ep + (size_t)ia.y * EMBED_DIM + off);
            unsigned a2 = *(const unsigned*)(ep + (size_t)ia.z * EMBED_DIM + off);
            unsigned a3 = *(const unsigned*)(ep + (size_t)ia.w * EMBED_DIM + off);
            accA.x += (bf2f_lo(a0) + bf2f_lo(a1)) + (bf2f_lo(a2) + bf2f_lo(a3));
            accA.y += (bf2f_hi(a0) + bf2f_hi(a1)) + (bf2f_hi(a2) + bf2f_hi(a3));
        }
        for (int tb = t; tb < gb; tb++) {
            int4 ib = gB[tb];
            unsigned b0 = *(const unsigned*)(ep + (size_t)ib.x * EMBED_DIM + off);
            unsigned b1 = *(const unsigned*)(ep + (size_t)ib.y * EMBED_DIM + off);
            unsigned b2 = *(const unsigned*)(ep + (size_t)ib.z * EMBED_DIM + off);
            unsigned b3 = *(const unsigned*)(ep + (size_t)ib.w * EMBED_DIM + off);
            accB.x += (bf2f_lo(b0) + bf2f_lo(b1)) + (bf2f_lo(b2) + bf2f_lo(b3));
            accB.y += (bf2f_hi(b0) + bf2f_hi(b1)) + (bf2f_hi(b2) + bf2f_hi(b3));
        }
        float invA = (cN[nA] > 0) ? 1.0f / (float)cN[nA] : 0.0f;
        float invB = (cN[nB] > 0) ? 1.0f / (float)cN[nB] : 0.0f;
        unsigned oA = (unsigned)f2bf_rne(accA.x * invA) | ((unsigned)f2bf_rne(accA.y * invA) << 16);
        unsigned oB = (unsigned)f2bf_rne(accB.x * invB) | ((unsigned)f2bf_rne(accB.y * invB) << 16);
        *(unsigned*)(sa + (wave * 8 + nA) * LDS_S + off) = oA;
        *(unsigned*)(sa + (wave * 8 + nB) * LDS_S + off) = oB;
    }

    // ---- write self slab to LDS (loads issued at kernel top) ----
    {
        int g = tid, row = g >> 4, c = g & 15;
        *(int4*)(se + row * LDS_S + c * 8) = ve0;
        g = 256 + tid; row = g >> 4; c = g & 15;
        *(int4*)(se + row * LDS_S + c * 8) = ve1;
    }

    // ---- W fragments + bias (latency hides under the barrier wait) ----
    int jt0 = wave * 2;
    bf16x8 wl[2][4], wr[2][4];
#pragma unroll
    for (int jj = 0; jj < 2; jj++) {
#pragma unroll
        for (int kt = 0; kt < 4; kt++) {
            size_t o = (size_t)((((jt0 + jj) * 4 + kt) * 64 + lane)) * 8;
            wl[jj][kt] = *(const bf16x8*)((const __bf16*)wlsw + o);
            wr[jj][kt] = *(const bf16x8*)((const __bf16*)wrsw + o);
        }
    }
    float bias[2];
    bias[0] = bl[(jt0 + 0) * 16 + m];
    bias[1] = bl[(jt0 + 1) * 16 + m];

    __syncthreads();   // all waves' sa flushes + se writes visible

    // ---- phase 2: af from sa; ef from se; MFMA; direct store ----
#pragma unroll
    for (int rt = 0; rt < 2; rt++) {
        bf16x8 af[4], ef[4];
#pragma unroll
        for (int kt = 0; kt < 4; kt++) {
            int o = (rt * 16 + m) * LDS_S + kt * 32 + quad * 8;
            af[kt] = *(const bf16x8*)(sa + o);
            ef[kt] = *(const bf16x8*)(se + o);
        }
        f32x4 acc[2] = {{0.f,0.f,0.f,0.f}, {0.f,0.f,0.f,0.f}};
#pragma unroll
        for (int kt = 0; kt < 4; kt++) {
#pragma unroll
            for (int jj = 0; jj < 2; jj++) {
                acc[jj] = __builtin_amdgcn_mfma_f32_16x16x32_bf16(af[kt], wl[jj][kt], acc[jj], 0, 0, 0);
                acc[jj] = __builtin_amdgcn_mfma_f32_16x16x32_bf16(ef[kt], wr[jj][kt], acc[jj], 0, 0, 0);
            }
        }
        // C/D layout: col = lane&15, row = quad*4 + reg
#pragma unroll
        for (int jj = 0; jj < 2; jj++) {
#pragma unroll
            for (int r = 0; r < 4; r++) {
                int orow = node0 + rt * 16 + quad * 4 + r;
                out[(size_t)orow * EMBED_DIM + (jt0 + jj) * 16 + m] = acc[jj][r] + bias[jj];
            }
        }
    }
}

extern "C" void kernel_launch(void* const* d_in, const int* in_sizes, int n_in,
                              void* d_out, int out_size, void* d_ws, size_t ws_size,
                              hipStream_t stream) {
    const float* emb = (const float*)d_in[0];
    const float* Wl  = (const float*)d_in[1];
    const float* bl  = (const float*)d_in[2];
    const float* Wr  = (const float*)d_in[3];
    const int*   src = (const int*)d_in[4];
    const int*   dst = (const int*)d_in[5];
    float* out = (float*)d_out;

    char* ws = (char*)d_ws;
    unsigned short* embb   = (unsigned short*)ws;
    int*            cursor = (int*)(ws + OFF_CURSOR);
    int*            perm   = (int*)(ws + OFF_PERM);
    unsigned short* wlsw   = (unsigned short*)(ws + OFF_WLSW);
    unsigned short* wrsw   = (unsigned short*)(ws + OFF_WRSW);

    // zero scatter cursors (graph-capturable memset node)
    hipMemsetAsync(ws + OFF_CURSOR, 0, 400000, stream);

    k_init<<<GRID_INIT, 256, 0, stream>>>(emb, Wl, Wr, src, dst, embb, cursor, perm, wlsw, wrsw);
    k_fused<<<3125, 256, 0, stream>>>(embb, cursor, perm, wlsw, wrsw, bl, out);
}

// Round 12
// 180.612 us; speedup vs baseline: 1.1022x; 1.0068x over previous
//
#include <hip/hip_runtime.h>
#include <hip/hip_bf16.h>

#define N_USERS   100000
#define EMBED_DIM 128
#define N_EDGES   640000
#define SLOTS     32               // fixed perm capacity per node (max deg << 32)
#define GRID_INIT 20000            // 8 XCD-class blocks per 256-edge window

typedef __bf16 bf16x8 __attribute__((ext_vector_type(8)));
typedef float  f32x4  __attribute__((ext_vector_type(4)));
typedef float  f32x2  __attribute__((ext_vector_type(2)));

// ---- workspace layout (bytes) ----
// [0,          25,600,384)  embb   bf16 [100001][128]  row 0 = zeros, node n -> row n+1
// [25,600,384, 38,400,512)  embf8  fp8  [100001][128]  e4m3(16*emb), row 0 = zeros
// [38,400,512, 38,800,512)  cursor int  [100000]       (scatter cursor == degree)
// [38,800,512, 51,600,512)  perm   int  [100000][32]   ids are src+1; memset-0 pads
//                                                       read row 0 = zero row (no
//                                                       pad stores, no clamps)
// [51,600,512, 51,633,280)  wlsw   bf16 [16384]  Wl in MFMA-fragment order
// [51,633,280, 51,666,048)  wrsw   bf16 [16384]  Wr in MFMA-fragment order
// ONE memset covers cursor+perm (13.2 MB, contiguous).
#define OFF_EMBF8  25600384
#define OFF_CURSOR 38400512
#define OFF_PERM   38800512
#define OFF_WLSW   51600512
#define OFF_WRSW   51633280

__device__ __forceinline__ unsigned short f2bf_rne(float f) {
    union { float f; unsigned u; } c; c.f = f;
    unsigned u = c.u + 0x7fffu + ((c.u >> 16) & 1u);
    return (unsigned short)(u >> 16);
}
__device__ __forceinline__ float bf2f_lo(unsigned u) {
    union { float f; unsigned u; } c; c.u = u << 16;
    return c.f;
}
__device__ __forceinline__ float bf2f_hi(unsigned u) {
    union { float f; unsigned u; } c; c.u = u & 0xffff0000u;
    return c.f;
}

// ---- fp8 e4m3fn helpers (HW cvt when available; manual RNE fallback) ----
__device__ __forceinline__ unsigned char f32_to_fp8_sw(float x) {
    union { float f; unsigned u; } c; c.f = x;
    unsigned s = (c.u >> 24) & 0x80u;
    float a = fabsf(x);
    if (a >= 448.0f) return (unsigned char)(s | 0x7E);
    if (a >= 0.015625f) {                       // normal: 1.mmm * 2^(E-7)
        unsigned m = c.u & 0x7fffffffu;
        unsigned r = m + 0x7ffffu + ((m >> 20) & 1u);   // RNE at bit 20
        int e32 = (int)(r >> 23) - 127;
        unsigned man3 = (r >> 20) & 0x7u;
        int E = e32 + 7;
        if (E >= 16) return (unsigned char)(s | 0x7E);
        return (unsigned char)(s | (E << 3) | man3);
    }
    int n = (int)rintf(a * 512.0f);             // subnormal: units of 2^-9
    if (n >= 8) return (unsigned char)(s | 0x08);
    return (unsigned char)(s | n);
}
__device__ __forceinline__ float fp8_to_f32_sw(unsigned char b) {
    unsigned s = ((unsigned)b & 0x80u) << 24;
    unsigned E = (b >> 3) & 0xFu;
    unsigned m = b & 7u;
    union { unsigned u; float f; } c;
    if (E == 0) { c.f = (float)m * 0.001953125f; c.u |= s; return c.f; }
    c.u = s | ((E + 120u) << 23) | (m << 20);
    return c.f;
}
__device__ __forceinline__ unsigned enc_fp8x2(float x, float y) {
#if __has_builtin(__builtin_amdgcn_cvt_pk_fp8_f32)
    return (unsigned)__builtin_amdgcn_cvt_pk_fp8_f32(x, y, 0, false) & 0xffffu;
#else
    return (unsigned)f32_to_fp8_sw(x) | ((unsigned)f32_to_fp8_sw(y) << 8);
#endif
}
__device__ __forceinline__ f32x2 dec_fp8x2(unsigned short u) {
#if __has_builtin(__builtin_amdgcn_cvt_pk_f32_fp8)
    return __builtin_amdgcn_cvt_pk_f32_fp8((unsigned)u, false);
#else
    f32x2 r;
    r[0] = fp8_to_f32_sw((unsigned char)(u & 0xff));
    r[1] = fp8_to_f32_sw((unsigned char)(u >> 8));
    return r;
#endif
}

// Prep: emb -> embb bf16 (rows shifted +1; row 0 zeros) AND embf8 fp8
// (e4m3 of 16*emb -- x16 pre-scale keeps values in fp8-normal range; the
// 1/16 folds into the mean divisor), W_l/W_r MFMA-fragment swizzle, and the
// XCD-partitioned edge scatter (R11): window w = b>>3, class c = b&7 keeps
// edges with ((dst>>4)&7)==c so each cursor line + its perm rows are written
// from ONE XCD class. perm ids stored as src+1; memset-0 slots beyond the
// degree read row 0 = zeros (pads for free).
// cursor+perm pre-zeroed by one hipMemsetAsync.  grid: 20000 x 256
__global__ __launch_bounds__(256) void k_init(const float* __restrict__ emb,
                                              const float* __restrict__ Wl,
                                              const float* __restrict__ Wr,
                                              const int* __restrict__ src,
                                              const int* __restrict__ dst,
                                              unsigned short* __restrict__ embb,
                                              unsigned char* __restrict__ embf8,
                                              int* __restrict__ cursor,
                                              int* __restrict__ perm,
                                              unsigned short* __restrict__ wlsw,
                                              unsigned short* __restrict__ wrsw) {
    int b   = blockIdx.x;
    int tid = threadIdx.x;

    // ---- edge scatter, XCD-class-filtered ----
    {
        int w = b >> 3;            // window 0..2499
        int cls = b & 7;           // XCD class
        int e = w * 256 + tid;     // covers 0..639,999 exactly
        int d = dst[e];
        if (((d >> 4) & 7) == cls) {
            int pos = atomicAdd(&cursor[d], 1);
            if (pos < SLOTS) perm[d * SLOTS + pos] = src[e] + 1;
        }
    }

    // ---- conversion + W swizzle (blocks < 6250 only) ----
    if (b < 6250) {
        int i = b * 256 + tid;
        if (i < 2048) {    // 2048 threads x 8 elems = 16384 = one W table
            int li = i & 63;            // lane
            int kt = (i >> 6) & 3;
            int jt = i >> 8;            // 0..7
            int row  = jt * 16 + (li & 15);
            int colb = kt * 32 + ((li >> 4) << 3);
            const float4* pl = (const float4*)(Wl + row * 128 + colb);
            const float4* pr = (const float4*)(Wr + row * 128 + colb);
            float4 l0 = pl[0], l1 = pl[1];
            float4 r0 = pr[0], r1 = pr[1];
            int o = i * 8;
            wlsw[o+0] = f2bf_rne(l0.x); wlsw[o+1] = f2bf_rne(l0.y);
            wlsw[o+2] = f2bf_rne(l0.z); wlsw[o+3] = f2bf_rne(l0.w);
            wlsw[o+4] = f2bf_rne(l1.x); wlsw[o+5] = f2bf_rne(l1.y);
            wlsw[o+6] = f2bf_rne(l1.z); wlsw[o+7] = f2bf_rne(l1.w);
            wrsw[o+0] = f2bf_rne(r0.x); wrsw[o+1] = f2bf_rne(r0.y);
            wrsw[o+2] = f2bf_rne(r0.z); wrsw[o+3] = f2bf_rne(r0.w);
            wrsw[o+4] = f2bf_rne(r1.x); wrsw[o+5] = f2bf_rne(r1.y);
            wrsw[o+6] = f2bf_rne(r1.z); wrsw[o+7] = f2bf_rne(r1.w);
        }
        // zero row 0: embb 256 B (16 int4), embf8 128 B (8 int4)
        if (i < 16) {
            int4 z = {0, 0, 0, 0};
            ((int4*)embb)[i] = z;
            if (i < 8) ((int4*)embf8)[i] = z;
        }
        // emb -> embb (row-shifted +1) and embf8 (16x scale), 8 floats/thread
        float4 a = ((const float4*)emb)[i * 2 + 0];
        float4 bb = ((const float4*)emb)[i * 2 + 1];
        int4 p;
        p.x = (int)f2bf_rne(a.x)  | ((int)f2bf_rne(a.y)  << 16);
        p.y = (int)f2bf_rne(a.z)  | ((int)f2bf_rne(a.w)  << 16);
        p.z = (int)f2bf_rne(bb.x) | ((int)f2bf_rne(bb.y) << 16);
        p.w = (int)f2bf_rne(bb.z) | ((int)f2bf_rne(bb.w) << 16);
        ((int4*)(embb + EMBED_DIM))[i] = p;     // +1 row shift (128 shorts)
        uint2 q;
        q.x = enc_fp8x2(a.x * 16.0f, a.y * 16.0f)
            | (enc_fp8x2(a.z * 16.0f, a.w * 16.0f) << 16);
        q.y = enc_fp8x2(bb.x * 16.0f, bb.y * 16.0f)
            | (enc_fp8x2(bb.z * 16.0f, bb.w * 16.0f) << 16);
        ((uint2*)(embf8 + EMBED_DIM))[i] = q;   // +1 row shift (128 bytes)
    }
}

// FUSED aggregate + matmul: block = 32 nodes x 128 cols, 4 waves.
// Gather reads the FP8 table: 128 B/row = ONE cache line per request (halves
//   both bytes and L2-request count vs bf16's 256 B -- R11 analysis: six
//   gather structures converged at 50-64us with all pipes idle => aggregate
//   random-read service bound; only traffic reduction moves it).
//   Decode via v_cvt_pk_f32_fp8 (1 instr -> 2 floats). Pads are free: memset-0
//   perm slots read row 0 = zeros (no pad stores, no clamps, one less barrier).
// Self/MFMA path stays bf16 (un-averaged errors there would eat the budget):
//   ve0/ve1 slab loads issued FIRST (R10-proven), se LDS slab, pre-swizzled W.
// Mean divisor folds the fp8 1/16 pre-scale: iv = 0.0625/deg.
// grid: 3125 x 256
#define LDS_S 136
__global__ __launch_bounds__(256) void k_fused(const unsigned short* __restrict__ embb,
                                               const unsigned char* __restrict__ embf8,
                                               const int* __restrict__ cursor,
                                               const int* __restrict__ perm,
                                               const unsigned short* __restrict__ wlsw,
                                               const unsigned short* __restrict__ wrsw,
                                               const float* __restrict__ bl,
                                               float* __restrict__ out) {
    __shared__ unsigned short sa[32 * LDS_S];   // 8,704 B bf16 neighbor means
    __shared__ unsigned short se[32 * LDS_S];   // 8,704 B bf16 self rows
    int tid  = threadIdx.x;
    int wave = tid >> 6;
    int lane = tid & 63;
    int quad = lane >> 4;      // 0..3
    int m    = lane & 15;
    int node0 = blockIdx.x * 32;
    int off   = lane * 2;      // column pair this lane owns

    // ---- issue self-slab loads FIRST: 2 x 8 KB contiguous (rows +1 shift) ----
    const int4* eslab = (const int4*)(embb + ((size_t)node0 + 1) * EMBED_DIM);
    int4 ve0 = eslab[tid];
    int4 ve1 = eslab[256 + tid];

    // ---- all 8 node degrees up front (L2-hot, independent loads) ----
    int nb = node0 + wave * 8;
    int cN[8];
#pragma unroll
    for (int r = 0; r < 8; r++) {
        int c = cursor[nb + r];
        cN[r] = c < SLOTS ? c : SLOTS;
    }

    // ---- phase 1: branch-free pair-interleaved FP8 gather ----
#pragma unroll
    for (int p = 0; p < 4; p++) {
        int nA = p * 2, nB = nA + 1;
        const int4* gA = (const int4*)(perm + (nb + nA) * SLOTS);
        const int4* gB = (const int4*)(perm + (nb + nB) * SLOTS);
        int ga = (cN[nA] + 3) >> 2;
        int gb = (cN[nB] + 3) >> 2;
        int gmin = ga < gb ? ga : gb;
        float2 accA = {0.f, 0.f}, accB = {0.f, 0.f};
        int t = 0;
#pragma unroll 2
        for (; t < gmin; t++) {                // 8 one-line row-requests in flight
            int4 ia = gA[t];                   // wave-uniform broadcast
            int4 ib = gB[t];
            unsigned short a0 = *(const unsigned short*)(embf8 + (size_t)ia.x * EMBED_DIM + off);
            unsigned short a1 = *(const unsigned short*)(embf8 + (size_t)ia.y * EMBED_DIM + off);
            unsigned short a2 = *(const unsigned short*)(embf8 + (size_t)ia.z * EMBED_DIM + off);
            unsigned short a3 = *(const unsigned short*)(embf8 + (size_t)ia.w * EMBED_DIM + off);
            unsigned short b0 = *(const unsigned short*)(embf8 + (size_t)ib.x * EMBED_DIM + off);
            unsigned short b1 = *(const unsigned short*)(embf8 + (size_t)ib.y * EMBED_DIM + off);
            unsigned short b2 = *(const unsigned short*)(embf8 + (size_t)ib.z * EMBED_DIM + off);
            unsigned short b3 = *(const unsigned short*)(embf8 + (size_t)ib.w * EMBED_DIM + off);
            f32x2 fa0 = dec_fp8x2(a0), fa1 = dec_fp8x2(a1);
            f32x2 fa2 = dec_fp8x2(a2), fa3 = dec_fp8x2(a3);
            f32x2 fb0 = dec_fp8x2(b0), fb1 = dec_fp8x2(b1);
            f32x2 fb2 = dec_fp8x2(b2), fb3 = dec_fp8x2(b3);
            accA.x += (fa0[0] + fa1[0]) + (fa2[0] + fa3[0]);
            accA.y += (fa0[1] + fa1[1]) + (fa2[1] + fa3[1]);
            accB.x += (fb0[0] + fb1[0]) + (fb2[0] + fb3[0]);
            accB.y += (fb0[1] + fb1[1]) + (fb2[1] + fb3[1]);
        }
        for (int ta = t; ta < ga; ta++) {
            int4 ia = gA[ta];
            unsigned short a0 = *(const unsigned short*)(embf8 + (size_t)ia.x * EMBED_DIM + off);
            unsigned short a1 = *(const unsigned short*)(embf8 + (size_t)ia.y * EMBED_DIM + off);
            unsigned short a2 = *(const unsigned short*)(embf8 + (size_t)ia.z * EMBED_DIM + off);
            unsigned short a3 = *(const unsigned short*)(embf8 + (size_t)ia.w * EMBED_DIM + off);
            f32x2 fa0 = dec_fp8x2(a0), fa1 = dec_fp8x2(a1);
            f32x2 fa2 = dec_fp8x2(a2), fa3 = dec_fp8x2(a3);
            accA.x += (fa0[0] + fa1[0]) + (fa2[0] + fa3[0]);
            accA.y += (fa0[1] + fa1[1]) + (fa2[1] + fa3[1]);
        }
        for (int tb = t; tb < gb; tb++) {
            int4 ib = gB[tb];
            unsigned short b0 = *(const unsigned short*)(embf8 + (size_t)ib.x * EMBED_DIM + off);
            unsigned short b1 = *(const unsigned short*)(embf8 + (size_t)ib.y * EMBED_DIM + off);
            unsigned short b2 = *(const unsigned short*)(embf8 + (size_t)ib.z * EMBED_DIM + off);
            unsigned short b3 = *(const unsigned short*)(embf8 + (size_t)ib.w * EMBED_DIM + off);
            f32x2 fb0 = dec_fp8x2(b0), fb1 = dec_fp8x2(b1);
            f32x2 fb2 = dec_fp8x2(b2), fb3 = dec_fp8x2(b3);
            accB.x += (fb0[0] + fb1[0]) + (fb2[0] + fb3[0]);
            accB.y += (fb0[1] + fb1[1]) + (fb2[1] + fb3[1]);
        }
        // mean with folded 1/16 fp8 pre-scale
        float invA = (cN[nA] > 0) ? 0.0625f / (float)cN[nA] : 0.0f;
        float invB = (cN[nB] > 0) ? 0.0625f / (float)cN[nB] : 0.0f;
        unsigned oA = (unsigned)f2bf_rne(accA.x * invA) | ((unsigned)f2bf_rne(accA.y * invA) << 16);
        unsigned oB = (unsigned)f2bf_rne(accB.x * invB) | ((unsigned)f2bf_rne(accB.y * invB) << 16);
        *(unsigned*)(sa + (wave * 8 + nA) * LDS_S + off) = oA;
        *(unsigned*)(sa + (wave * 8 + nB) * LDS_S + off) = oB;
    }

    // ---- write self slab to LDS (loads issued at kernel top) ----
    {
        int g = tid, row = g >> 4, c = g & 15;
        *(int4*)(se + row * LDS_S + c * 8) = ve0;
        g = 256 + tid; row = g >> 4; c = g & 15;
        *(int4*)(se + row * LDS_S + c * 8) = ve1;
    }

    // ---- W fragments + bias (latency hides under the barrier wait) ----
    int jt0 = wave * 2;
    bf16x8 wl[2][4], wr[2][4];
#pragma unroll
    for (int jj = 0; jj < 2; jj++) {
#pragma unroll
        for (int kt = 0; kt < 4; kt++) {
            size_t o = (size_t)((((jt0 + jj) * 4 + kt) * 64 + lane)) * 8;
            wl[jj][kt] = *(const bf16x8*)((const __bf16*)wlsw + o);
            wr[jj][kt] = *(const bf16x8*)((const __bf16*)wrsw + o);
        }
    }
    float bias[2];
    bias[0] = bl[(jt0 + 0) * 16 + m];
    bias[1] = bl[(jt0 + 1) * 16 + m];

    __syncthreads();   // all waves' sa flushes + se writes visible

    // ---- phase 2: af from sa; ef from se; MFMA; direct store ----
#pragma unroll
    for (int rt = 0; rt < 2; rt++) {
        bf16x8 af[4], ef[4];
#pragma unroll
        for (int kt = 0; kt < 4; kt++) {
            int o = (rt * 16 + m) * LDS_S + kt * 32 + quad * 8;
            af[kt] = *(const bf16x8*)(sa + o);
            ef[kt] = *(const bf16x8*)(se + o);
        }
        f32x4 acc[2] = {{0.f,0.f,0.f,0.f}, {0.f,0.f,0.f,0.f}};
#pragma unroll
        for (int kt = 0; kt < 4; kt++) {
#pragma unroll
            for (int jj = 0; jj < 2; jj++) {
                acc[jj] = __builtin_amdgcn_mfma_f32_16x16x32_bf16(af[kt], wl[jj][kt], acc[jj], 0, 0, 0);
                acc[jj] = __builtin_amdgcn_mfma_f32_16x16x32_bf16(ef[kt], wr[jj][kt], acc[jj], 0, 0, 0);
            }
        }
        // C/D layout: col = lane&15, row = quad*4 + reg
#pragma unroll
        for (int jj = 0; jj < 2; jj++) {
#pragma unroll
            for (int r = 0; r < 4; r++) {
                int orow = node0 + rt * 16 + quad * 4 + r;
                out[(size_t)orow * EMBED_DIM + (jt0 + jj) * 16 + m] = acc[jj][r] + bias[jj];
            }
        }
    }
}

extern "C" void kernel_launch(void* const* d_in, const int* in_sizes, int n_in,
                              void* d_out, int out_size, void* d_ws, size_t ws_size,
                              hipStream_t stream) {
    const float* emb = (const float*)d_in[0];
    const float* Wl  = (const float*)d_in[1];
    const float* bl  = (const float*)d_in[2];
    const float* Wr  = (const float*)d_in[3];
    const int*   src = (const int*)d_in[4];
    const int*   dst = (const int*)d_in[5];
    float* out = (float*)d_out;

    char* ws = (char*)d_ws;
    unsigned short* embb   = (unsigned short*)ws;
    unsigned char*  embf8  = (unsigned char*)(ws + OFF_EMBF8);
    int*            cursor = (int*)(ws + OFF_CURSOR);
    int*            perm   = (int*)(ws + OFF_PERM);
    unsigned short* wlsw   = (unsigned short*)(ws + OFF_WLSW);
    unsigned short* wrsw   = (unsigned short*)(ws + OFF_WRSW);

    // ONE memset zeroes cursor AND perm (pads become id 0 = zero row)
    hipMemsetAsync(ws + OFF_CURSOR, 0, 400000 + 12800000, stream);

    k_init<<<GRID_INIT, 256, 0, stream>>>(emb, Wl, Wr, src, dst, embb, embf8,
                                          cursor, perm, wlsw, wrsw);
    k_fused<<<3125, 256, 0, stream>>>(embb, embf8, cursor, perm, wlsw, wrsw, bl, out);
}

// Round 13
// 175.365 us; speedup vs baseline: 1.1351x; 1.0299x over previous
//
#include <hip/hip_runtime.h>
#include <hip/hip_bf16.h>

#define N_USERS   100000
#define EMBED_DIM 128
#define N_EDGES   640000
#define SLOTS     32               // fixed perm capacity per node (max deg << 32)
#define GRID_INIT 10000            // 8 XCD-class blocks per 512-edge window

typedef __bf16 bf16x8 __attribute__((ext_vector_type(8)));
typedef float  f32x4  __attribute__((ext_vector_type(4)));
typedef float  f32x2  __attribute__((ext_vector_type(2)));

// ---- workspace layout (bytes) ----
// [0,          12,800,128)  embf8  fp8  [100001][128]  e4m3(16*emb), row 0 = zeros,
//                                                       node n -> row n+1
// [12,800,256, 13,200,256)  cursor int  [100000]       (scatter cursor == degree)
// [13,200,256, 26,000,256)  perm   int  [100000][32]   ids are src+1; memset-0 pads
//                                                       read row 0 = zero row
// [26,000,256, 26,033,024)  wlsw   bf16 [16384]  Wl in MFMA-fragment order
// [26,033,024, 26,065,792)  wrsw   bf16 [16384]  Wr in MFMA-fragment order
// ONE memset covers cursor+perm (13.2 MB, contiguous).  embb is GONE (R12
// lesson: its only consumer was a contiguous read -- k_fused reads emb fp32).
#define OFF_CURSOR 12800256
#define OFF_PERM   13200256
#define OFF_WLSW   26000256
#define OFF_WRSW   26033024

__device__ __forceinline__ unsigned short f2bf_rne(float f) {
    union { float f; unsigned u; } c; c.f = f;
    unsigned u = c.u + 0x7fffu + ((c.u >> 16) & 1u);
    return (unsigned short)(u >> 16);
}

// ---- fp8 e4m3fn helpers (HW cvt when available; manual RNE fallback) ----
__device__ __forceinline__ unsigned char f32_to_fp8_sw(float x) {
    union { float f; unsigned u; } c; c.f = x;
    unsigned s = (c.u >> 24) & 0x80u;
    float a = fabsf(x);
    if (a >= 448.0f) return (unsigned char)(s | 0x7E);
    if (a >= 0.015625f) {                       // normal: 1.mmm * 2^(E-7)
        unsigned m = c.u & 0x7fffffffu;
        unsigned r = m + 0x7ffffu + ((m >> 20) & 1u);   // RNE at bit 20
        int e32 = (int)(r >> 23) - 127;
        unsigned man3 = (r >> 20) & 0x7u;
        int E = e32 + 7;
        if (E >= 16) return (unsigned char)(s | 0x7E);
        return (unsigned char)(s | (E << 3) | man3);
    }
    int n = (int)rintf(a * 512.0f);             // subnormal: units of 2^-9
    if (n >= 8) return (unsigned char)(s | 0x08);
    return (unsigned char)(s | n);
}
__device__ __forceinline__ float fp8_to_f32_sw(unsigned char b) {
    unsigned s = ((unsigned)b & 0x80u) << 24;
    unsigned E = (b >> 3) & 0xFu;
    unsigned m = b & 7u;
    union { unsigned u; float f; } c;
    if (E == 0) { c.f = (float)m * 0.001953125f; c.u |= s; return c.f; }
    c.u = s | ((E + 120u) << 23) | (m << 20);
    return c.f;
}
__device__ __forceinline__ unsigned enc_fp8x2(float x, float y) {
#if __has_builtin(__builtin_amdgcn_cvt_pk_fp8_f32)
    return (unsigned)__builtin_amdgcn_cvt_pk_fp8_f32(x, y, 0, false) & 0xffffu;
#else
    return (unsigned)f32_to_fp8_sw(x) | ((unsigned)f32_to_fp8_sw(y) << 8);
#endif
}
__device__ __forceinline__ f32x2 dec_fp8x2(unsigned short u) {
#if __has_builtin(__builtin_amdgcn_cvt_pk_f32_fp8)
    return __builtin_amdgcn_cvt_pk_f32_fp8((unsigned)u, false);
#else
    f32x2 r;
    r[0] = fp8_to_f32_sw((unsigned char)(u & 0xff));
    r[1] = fp8_to_f32_sw((unsigned char)(u >> 8));
    return r;
#endif
}

// Prep: emb -> embf8 fp8 (e4m3 of 16*emb; 1/16 folds into the mean divisor;
// rows shifted +1, row 0 zeros), W_l/W_r MFMA-fragment swizzle, and the
// XCD-partitioned edge scatter. R12 lessons applied:
//  - embb write REMOVED (k_fused reads emb fp32 directly for self rows)
//  - conversion emb loads issued BEFORE the scatter's dependent atomic chain
//    (the chain's ~1000cy latency hides under the streaming loads)
//  - 2 edges/thread: two independent atomic chains in flight
// Scatter: window w = b>>3 (512 edges), class c = b&7; the 8 blocks sharing a
// window land on 8 XCDs (blockIdx%8 round-robin); block keeps edges with
// ((dst>>4)&7)==c so each cursor line + its perm rows are written from ONE
// XCD class. perm ids stored src+1; memset-0 pad slots read row 0 = zeros.
// cursor+perm pre-zeroed by one hipMemsetAsync.  grid: 10000 x 256
__global__ __launch_bounds__(256) void k_init(const float* __restrict__ emb,
                                              const float* __restrict__ Wl,
                                              const float* __restrict__ Wr,
                                              const int* __restrict__ src,
                                              const int* __restrict__ dst,
                                              unsigned char* __restrict__ embf8,
                                              int* __restrict__ cursor,
                                              int* __restrict__ perm,
                                              unsigned short* __restrict__ wlsw,
                                              unsigned short* __restrict__ wrsw) {
    int b   = blockIdx.x;
    int tid = threadIdx.x;
    bool conv = (b < 6250);
    int i = b * 256 + tid;

    // ---- issue conversion loads FIRST (streaming, hides the scatter chain) ----
    float4 a, bb;
    if (conv) {
        a  = ((const float4*)emb)[i * 2 + 0];
        bb = ((const float4*)emb)[i * 2 + 1];
    }

    // ---- edge scatter, XCD-class-filtered, 2 edges/thread ----
    {
        int w   = b >> 3;              // window 0..1249 (512 edges each)
        int cls = b & 7;               // XCD class
        int e0 = w * 512 + tid;        // two independent chains
        int e1 = e0 + 256;
        int d0 = dst[e0];
        int d1 = dst[e1];
        if (((d0 >> 4) & 7) == cls) {
            int pos = atomicAdd(&cursor[d0], 1);
            if (pos < SLOTS) perm[d0 * SLOTS + pos] = src[e0] + 1;
        }
        if (((d1 >> 4) & 7) == cls) {
            int pos = atomicAdd(&cursor[d1], 1);
            if (pos < SLOTS) perm[d1 * SLOTS + pos] = src[e1] + 1;
        }
    }

    // ---- conversion + W swizzle (blocks < 6250 only) ----
    if (conv) {
        if (i < 2048) {    // 2048 threads x 8 elems = 16384 = one W table
            int li = i & 63;            // lane
            int kt = (i >> 6) & 3;
            int jt = i >> 8;            // 0..7
            int row  = jt * 16 + (li & 15);
            int colb = kt * 32 + ((li >> 4) << 3);
            const float4* pl = (const float4*)(Wl + row * 128 + colb);
            const float4* pr = (const float4*)(Wr + row * 128 + colb);
            float4 l0 = pl[0], l1 = pl[1];
            float4 r0 = pr[0], r1 = pr[1];
            int o = i * 8;
            wlsw[o+0] = f2bf_rne(l0.x); wlsw[o+1] = f2bf_rne(l0.y);
            wlsw[o+2] = f2bf_rne(l0.z); wlsw[o+3] = f2bf_rne(l0.w);
            wlsw[o+4] = f2bf_rne(l1.x); wlsw[o+5] = f2bf_rne(l1.y);
            wlsw[o+6] = f2bf_rne(l1.z); wlsw[o+7] = f2bf_rne(l1.w);
            wrsw[o+0] = f2bf_rne(r0.x); wrsw[o+1] = f2bf_rne(r0.y);
            wrsw[o+2] = f2bf_rne(r0.z); wrsw[o+3] = f2bf_rne(r0.w);
            wrsw[o+4] = f2bf_rne(r1.x); wrsw[o+5] = f2bf_rne(r1.y);
            wrsw[o+6] = f2bf_rne(r1.z); wrsw[o+7] = f2bf_rne(r1.w);
        }
        // zero row 0 of embf8: 128 B = 8 int4
        if (i < 8) {
            int4 z = {0, 0, 0, 0};
            ((int4*)embf8)[i] = z;
        }
        // emb -> embf8 (16x scale, row-shifted +1), 8 floats/thread
        uint2 q;
        q.x = enc_fp8x2(a.x * 16.0f, a.y * 16.0f)
            | (enc_fp8x2(a.z * 16.0f, a.w * 16.0f) << 16);
        q.y = enc_fp8x2(bb.x * 16.0f, bb.y * 16.0f)
            | (enc_fp8x2(bb.z * 16.0f, bb.w * 16.0f) << 16);
        ((uint2*)(embf8 + EMBED_DIM))[i] = q;   // +1 row shift (128 bytes)
    }
}

// FUSED aggregate + matmul: block = 32 nodes x 128 cols, 4 waves.
// Self slab now reads emb fp32 DIRECTLY (embb removed): 4 x 4KB contiguous
//   float4 loads issued at kernel top (latency hides under the gather), packed
//   to bf16 in-register with the SAME f2bf_rne as the old k_init conversion
//   -> bit-identical numerics, and k_init sheds a 25.6MB intermediate write.
// Phase 1 (gather): FP8 table, 128 B/row = ONE cache line per request (R12:
//   this is what finally moved the latency-bound gather). Pads free via
//   memset-0 perm slots reading row 0 = zeros. Decode v_cvt_pk_f32_fp8.
// Phase 2: af from sa; ef from se; W pre-swizzled; mean folds the fp8 1/16.
// grid: 3125 x 256
#define LDS_S 136
__global__ __launch_bounds__(256) void k_fused(const float* __restrict__ emb,
                                               const unsigned char* __restrict__ embf8,
                                               const int* __restrict__ cursor,
                                               const int* __restrict__ perm,
                                               const unsigned short* __restrict__ wlsw,
                                               const unsigned short* __restrict__ wrsw,
                                               const float* __restrict__ bl,
                                               float* __restrict__ out) {
    __shared__ unsigned short sa[32 * LDS_S];   // 8,704 B bf16 neighbor means
    __shared__ unsigned short se[32 * LDS_S];   // 8,704 B bf16 self rows
    int tid  = threadIdx.x;
    int wave = tid >> 6;
    int lane = tid & 63;
    int quad = lane >> 4;      // 0..3
    int m    = lane & 15;
    int node0 = blockIdx.x * 32;
    int off   = lane * 2;      // column pair this lane owns

    // ---- issue self-slab fp32 loads FIRST: 4 x 4 KB contiguous ----
    const float4* eslab = (const float4*)(emb + (size_t)node0 * EMBED_DIM);
    float4 ve0 = eslab[tid];
    float4 ve1 = eslab[256 + tid];
    float4 ve2 = eslab[512 + tid];
    float4 ve3 = eslab[768 + tid];

    // ---- all 8 node degrees up front (L2-hot, independent loads) ----
    int nb = node0 + wave * 8;
    int cN[8];
#pragma unroll
    for (int r = 0; r < 8; r++) {
        int c = cursor[nb + r];
        cN[r] = c < SLOTS ? c : SLOTS;
    }

    // ---- phase 1: branch-free pair-interleaved FP8 gather ----
#pragma unroll
    for (int p = 0; p < 4; p++) {
        int nA = p * 2, nB = nA + 1;
        const int4* gA = (const int4*)(perm + (nb + nA) * SLOTS);
        const int4* gB = (const int4*)(perm + (nb + nB) * SLOTS);
        int ga = (cN[nA] + 3) >> 2;
        int gb = (cN[nB] + 3) >> 2;
        int gmin = ga < gb ? ga : gb;
        float2 accA = {0.f, 0.f}, accB = {0.f, 0.f};
        int t = 0;
#pragma unroll 2
        for (; t < gmin; t++) {                // 8 one-line row-requests in flight
            int4 ia = gA[t];                   // wave-uniform broadcast
            int4 ib = gB[t];
            unsigned short a0 = *(const unsigned short*)(embf8 + (size_t)ia.x * EMBED_DIM + off);
            unsigned short a1 = *(const unsigned short*)(embf8 + (size_t)ia.y * EMBED_DIM + off);
            unsigned short a2 = *(const unsigned short*)(embf8 + (size_t)ia.z * EMBED_DIM + off);
            unsigned short a3 = *(const unsigned short*)(embf8 + (size_t)ia.w * EMBED_DIM + off);
            unsigned short b0 = *(const unsigned short*)(embf8 + (size_t)ib.x * EMBED_DIM + off);
            unsigned short b1 = *(const unsigned short*)(embf8 + (size_t)ib.y * EMBED_DIM + off);
            unsigned short b2 = *(const unsigned short*)(embf8 + (size_t)ib.z * EMBED_DIM + off);
            unsigned short b3 = *(const unsigned short*)(embf8 + (size_t)ib.w * EMBED_DIM + off);
            f32x2 fa0 = dec_fp8x2(a0), fa1 = dec_fp8x2(a1);
            f32x2 fa2 = dec_fp8x2(a2), fa3 = dec_fp8x2(a3);
            f32x2 fb0 = dec_fp8x2(b0), fb1 = dec_fp8x2(b1);
            f32x2 fb2 = dec_fp8x2(b2), fb3 = dec_fp8x2(b3);
            accA.x += (fa0[0] + fa1[0]) + (fa2[0] + fa3[0]);
            accA.y += (fa0[1] + fa1[1]) + (fa2[1] + fa3[1]);
            accB.x += (fb0[0] + fb1[0]) + (fb2[0] + fb3[0]);
            accB.y += (fb0[1] + fb1[1]) + (fb2[1] + fb3[1]);
        }
        for (int ta = t; ta < ga; ta++) {
            int4 ia = gA[ta];
            unsigned short a0 = *(const unsigned short*)(embf8 + (size_t)ia.x * EMBED_DIM + off);
            unsigned short a1 = *(const unsigned short*)(embf8 + (size_t)ia.y * EMBED_DIM + off);
            unsigned short a2 = *(const unsigned short*)(embf8 + (size_t)ia.z * EMBED_DIM + off);
            unsigned short a3 = *(const unsigned short*)(embf8 + (size_t)ia.w * EMBED_DIM + off);
            f32x2 fa0 = dec_fp8x2(a0), fa1 = dec_fp8x2(a1);
            f32x2 fa2 = dec_fp8x2(a2), fa3 = dec_fp8x2(a3);
            accA.x += (fa0[0] + fa1[0]) + (fa2[0] + fa3[0]);
            accA.y += (fa0[1] + fa1[1]) + (fa2[1] + fa3[1]);
        }
        for (int tb = t; tb < gb; tb++) {
            int4 ib = gB[tb];
            unsigned short b0 = *(const unsigned short*)(embf8 + (size_t)ib.x * EMBED_DIM + off);
            unsigned short b1 = *(const unsigned short*)(embf8 + (size_t)ib.y * EMBED_DIM + off);
            unsigned short b2 = *(const unsigned short*)(embf8 + (size_t)ib.z * EMBED_DIM + off);
            unsigned short b3 = *(const unsigned short*)(embf8 + (size_t)ib.w * EMBED_DIM + off);
            f32x2 fb0 = dec_fp8x2(b0), fb1 = dec_fp8x2(b1);
            f32x2 fb2 = dec_fp8x2(b2), fb3 = dec_fp8x2(b3);
            accB.x += (fb0[0] + fb1[0]) + (fb2[0] + fb3[0]);
            accB.y += (fb0[1] + fb1[1]) + (fb2[1] + fb3[1]);
        }
        // mean with folded 1/16 fp8 pre-scale
        float invA = (cN[nA] > 0) ? 0.0625f / (float)cN[nA] : 0.0f;
        float invB = (cN[nB] > 0) ? 0.0625f / (float)cN[nB] : 0.0f;
        unsigned oA = (unsigned)f2bf_rne(accA.x * invA) | ((unsigned)f2bf_rne(accA.y * invA) << 16);
        unsigned oB = (unsigned)f2bf_rne(accB.x * invB) | ((unsigned)f2bf_rne(accB.y * invB) << 16);
        *(unsigned*)(sa + (wave * 8 + nA) * LDS_S + off) = oA;
        *(unsigned*)(sa + (wave * 8 + nB) * LDS_S + off) = oB;
    }

    // ---- pack self slab to bf16 and write to LDS (loads issued at top;
    //      same f2bf_rne as the old embb path -> bit-identical) ----
    {
        uint2 q;
        int g;
        g = tid;
        q.x = (unsigned)f2bf_rne(ve0.x) | ((unsigned)f2bf_rne(ve0.y) << 16);
        q.y = (unsigned)f2bf_rne(ve0.z) | ((unsigned)f2bf_rne(ve0.w) << 16);
        *(uint2*)(se + (g >> 5) * LDS_S + (g & 31) * 4) = q;
        g = 256 + tid;
        q.x = (unsigned)f2bf_rne(ve1.x) | ((unsigned)f2bf_rne(ve1.y) << 16);
        q.y = (unsigned)f2bf_rne(ve1.z) | ((unsigned)f2bf_rne(ve1.w) << 16);
        *(uint2*)(se + (g >> 5) * LDS_S + (g & 31) * 4) = q;
        g = 512 + tid;
        q.x = (unsigned)f2bf_rne(ve2.x) | ((unsigned)f2bf_rne(ve2.y) << 16);
        q.y = (unsigned)f2bf_rne(ve2.z) | ((unsigned)f2bf_rne(ve2.w) << 16);
        *(uint2*)(se + (g >> 5) * LDS_S + (g & 31) * 4) = q;
        g = 768 + tid;
        q.x = (unsigned)f2bf_rne(ve3.x) | ((unsigned)f2bf_rne(ve3.y) << 16);
        q.y = (unsigned)f2bf_rne(ve3.z) | ((unsigned)f2bf_rne(ve3.w) << 16);
        *(uint2*)(se + (g >> 5) * LDS_S + (g & 31) * 4) = q;
    }

    // ---- W fragments + bias (latency hides under the barrier wait) ----
    int jt0 = wave * 2;
    bf16x8 wl[2][4], wr[2][4];
#pragma unroll
    for (int jj = 0; jj < 2; jj++) {
#pragma unroll
        for (int kt = 0; kt < 4; kt++) {
            size_t o = (size_t)((((jt0 + jj) * 4 + kt) * 64 + lane)) * 8;
            wl[jj][kt] = *(const bf16x8*)((const __bf16*)wlsw + o);
            wr[jj][kt] = *(const bf16x8*)((const __bf16*)wrsw + o);
        }
    }
    float bias[2];
    bias[0] = bl[(jt0 + 0) * 16 + m];
    bias[1] = bl[(jt0 + 1) * 16 + m];

    __syncthreads();   // all waves' sa flushes + se writes visible

    // ---- phase 2: af from sa; ef from se; MFMA; direct store ----
#pragma unroll
    for (int rt = 0; rt < 2; rt++) {
        bf16x8 af[4], ef[4];
#pragma unroll
        for (int kt = 0; kt < 4; kt++) {
            int o = (rt * 16 + m) * LDS_S + kt * 32 + quad * 8;
            af[kt] = *(const bf16x8*)(sa + o);
            ef[kt] = *(const bf16x8*)(se + o);
        }
        f32x4 acc[2] = {{0.f,0.f,0.f,0.f}, {0.f,0.f,0.f,0.f}};
#pragma unroll
        for (int kt = 0; kt < 4; kt++) {
#pragma unroll
            for (int jj = 0; jj < 2; jj++) {
                acc[jj] = __builtin_amdgcn_mfma_f32_16x16x32_bf16(af[kt], wl[jj][kt], acc[jj], 0, 0, 0);
                acc[jj] = __builtin_amdgcn_mfma_f32_16x16x32_bf16(ef[kt], wr[jj][kt], acc[jj], 0, 0, 0);
            }
        }
        // C/D layout: col = lane&15, row = quad*4 + reg
#pragma unroll
        for (int jj = 0; jj < 2; jj++) {
#pragma unroll
            for (int r = 0; r < 4; r++) {
                int orow = node0 + rt * 16 + quad * 4 + r;
                out[(size_t)orow * EMBED_DIM + (jt0 + jj) * 16 + m] = acc[jj][r] + bias[jj];
            }
        }
    }
}

extern "C" void kernel_launch(void* const* d_in, const int* in_sizes, int n_in,
                              void* d_out, int out_size, void* d_ws, size_t ws_size,
                              hipStream_t stream) {
    const float* emb = (const float*)d_in[0];
    const float* Wl  = (const float*)d_in[1];
    const float* bl  = (const float*)d_in[2];
    const float* Wr  = (const float*)d_in[3];
    const int*   src = (const int*)d_in[4];
    const int*   dst = (const int*)d_in[5];
    float* out = (float*)d_out;

    char* ws = (char*)d_ws;
    unsigned char*  embf8  = (unsigned char*)ws;
    int*            cursor = (int*)(ws + OFF_CURSOR);
    int*            perm   = (int*)(ws + OFF_PERM);
    unsigned short* wlsw   = (unsigned short*)(ws + OFF_WLSW);
    unsigned short* wrsw   = (unsigned short*)(ws + OFF_WRSW);

    // ONE memset zeroes cursor AND perm (pads become id 0 = zero row)
    hipMemsetAsync(ws + OFF_CURSOR, 0, 13200000, stream);

    k_init<<<GRID_INIT, 256, 0, stream>>>(emb, Wl, Wr, src, dst, embf8,
                                          cursor, perm, wlsw, wrsw);
    k_fused<<<3125, 256, 0, stream>>>(emb, embf8, cursor, perm, wlsw, wrsw, bl, out);
}